// Round 6
// baseline (148.027 us; speedup 1.0000x reference)
//
#include <hip/hip_runtime.h>
#include <hip/hip_bf16.h>
#include <hip/hip_cooperative_groups.h>

// MultiEmbedding: out1[r,:] = sum_{l<8} W[l, x1[r,l], :]
//                 out2[r,:] = sum_{l<4} W[l, x2[r,l], :]
// W: [8, 1024, 1024] fp32, x1: [8192,8] i32, x2: [8192,4] i32.
//
// Fused cooperative kernel (1024 blocks x 256 thr, 4 blocks/CU co-resident):
//   phase 1: W -> bf16 packed per column-slice wb[slice][l*1024+tok][128],
//            slice = blockIdx%8 -> XCD (round-robin dispatch). Normal stores
//            keep each XCD's 2 MiB slice in its private 4 MiB L2.
//   grid.sync()
//   phase 2: gather from the same slice on the same XCD -> L2-hit reads.
//            Output (never re-read) via nontemporal stores.

#define TOKEN_DIM 1024
#define N_TOKENS  1024
#define N_LEVELS  8

#define SLICES      8
#define SLICE_COLS  128                        // TOKEN_DIM / SLICES
#define SLICE_ROWS  (N_LEVELS * N_TOKENS)      // 8192 (l,token) rows
#define SLICE_ELEMS ((size_t)SLICE_ROWS * SLICE_COLS)  // 1M bf16 = 2 MiB

#define GRID_BLOCKS 1024
#define CHUNKS      (GRID_BLOCKS / SLICES)     // 128 chunks per slice

typedef float          f32x4 __attribute__((ext_vector_type(4)));
typedef unsigned short u16x4 __attribute__((ext_vector_type(4)));
typedef unsigned short u16x8 __attribute__((ext_vector_type(8)));

__device__ __forceinline__ unsigned short f2bf_rne(float f) {
    unsigned int u = __float_as_uint(f);
    u += 0x7fffu + ((u >> 16) & 1u);     // round-to-nearest-even
    return (unsigned short)(u >> 16);
}
__device__ __forceinline__ float bf2f(unsigned short u) {
    return __uint_as_float(((unsigned int)u) << 16);
}

// ---- fused cooperative kernel ----
__global__ __launch_bounds__(256, 4) void fused_embed_kernel(
    const int* __restrict__ x1, const int* __restrict__ x2,
    const float* __restrict__ w, unsigned short* __restrict__ wb,
    float* __restrict__ out, int n1, int n2)
{
    const int slice = blockIdx.x & 7;
    const int chunk = blockIdx.x >> 3;           // 0..127
    unsigned short* ws = wb + (size_t)slice * SLICE_ELEMS;

    // ---- phase 1: convert 64 (l,tok)-rows x 128 cols of this slice ----
    {
        const int lane_c = threadIdx.x & 31;     // 4 fp32 cols (16B)
        const int lrow   = threadIdx.x >> 5;     // 0..7
        const int row0   = chunk * 64;
        #pragma unroll
        for (int it = 0; it < 8; ++it) {
            const int row = row0 + it * 8 + lrow;            // l*1024 + tok
            const f32x4 v = *reinterpret_cast<const f32x4*>(
                w + (size_t)row * TOKEN_DIM + slice * SLICE_COLS + lane_c * 4);
            u16x4 o;
            o.x = f2bf_rne(v.x); o.y = f2bf_rne(v.y);
            o.z = f2bf_rne(v.z); o.w = f2bf_rne(v.w);
            *reinterpret_cast<u16x4*>(
                ws + (size_t)row * SLICE_COLS + lane_c * 4) = o;  // stays in L2
        }
    }

    cooperative_groups::this_grid().sync();

    // ---- phase 2: gather 128 output rows of this slice ----
    {
        const int g  = threadIdx.x & 15;         // 8 cols each
        const int lr = threadIdx.x >> 4;         // 0..15
        const int row0 = chunk * 128;
        const int col  = slice * SLICE_COLS + g * 8;
        const bool is_x1 = (chunk < 64);         // block-uniform (n1 = 8192)

        #pragma unroll 1
        for (int it = 0; it < 8; ++it) {
            const int row = row0 + it * 16 + lr;

            float acc[8];
            #pragma unroll
            for (int j = 0; j < 8; ++j) acc[j] = 0.f;

            if (is_x1) {
                const int* idx = x1 + (size_t)row * 8;
                u16x8 v[8];
                #pragma unroll
                for (int l = 0; l < 8; ++l) {
                    const int tok = idx[l];
                    v[l] = *reinterpret_cast<const u16x8*>(
                        ws + ((size_t)l * N_TOKENS + (size_t)tok) * SLICE_COLS + g * 8);
                }
                #pragma unroll
                for (int l = 0; l < 8; ++l)
                    #pragma unroll
                    for (int j = 0; j < 8; ++j) acc[j] += bf2f(v[l][j]);
            } else {
                const int r = row - n1;
                const int* idx = x2 + (size_t)r * 4;
                u16x8 v[4];
                #pragma unroll
                for (int l = 0; l < 4; ++l) {
                    const int tok = idx[l];
                    v[l] = *reinterpret_cast<const u16x8*>(
                        ws + ((size_t)l * N_TOKENS + (size_t)tok) * SLICE_COLS + g * 8);
                }
                #pragma unroll
                for (int l = 0; l < 4; ++l)
                    #pragma unroll
                    for (int j = 0; j < 8; ++j) acc[j] += bf2f(v[l][j]);
            }

            f32x4 lo = { acc[0], acc[1], acc[2], acc[3] };
            f32x4 hi = { acc[4], acc[5], acc[6], acc[7] };
            float* obase = out + (size_t)row * TOKEN_DIM + col;
            __builtin_nontemporal_store(lo, reinterpret_cast<f32x4*>(obase));
            __builtin_nontemporal_store(hi, reinterpret_cast<f32x4*>(obase) + 1);
        }
    }
}

// ---- fallback pass 1: fp32 -> bf16, packed per slice ----
__global__ __launch_bounds__(256) void convert_pack_kernel(
    const float* __restrict__ w, unsigned short* __restrict__ wb)
{
    const int slice  = blockIdx.x & 7;
    const int chunk  = blockIdx.x >> 3;      // 0..255
    const int lane_c = threadIdx.x & 31;
    const int lrow   = threadIdx.x >> 5;
    const int row0   = chunk * 32;
    unsigned short* ws = wb + (size_t)slice * SLICE_ELEMS;
    #pragma unroll
    for (int it = 0; it < 4; ++it) {
        const int row = row0 + it * 8 + lrow;
        const f32x4 v = *reinterpret_cast<const f32x4*>(
            w + (size_t)row * TOKEN_DIM + slice * SLICE_COLS + lane_c * 4);
        u16x4 o;
        o.x = f2bf_rne(v.x); o.y = f2bf_rne(v.y);
        o.z = f2bf_rne(v.z); o.w = f2bf_rne(v.w);
        *reinterpret_cast<u16x4*>(ws + (size_t)row * SLICE_COLS + lane_c * 4) = o;
    }
}

// ---- fallback pass 2: packed, column-sliced gather ----
__global__ __launch_bounds__(256) void gather_packed_kernel(
    const int* __restrict__ x1, const int* __restrict__ x2,
    const unsigned short* __restrict__ wb, float* __restrict__ out,
    int n1, int n2)
{
    const int slice = blockIdx.x & 7;
    const int chunk = blockIdx.x >> 3;
    const int row0  = chunk * 64;
    const int g     = threadIdx.x & 15;
    const int lr    = threadIdx.x >> 4;
    const unsigned short* ws = wb + (size_t)slice * SLICE_ELEMS;
    const int col = slice * SLICE_COLS + g * 8;
    const bool is_x1 = (row0 < n1);

    #pragma unroll
    for (int it = 0; it < 4; ++it) {
        const int row = row0 + it * 16 + lr;
        float acc[8];
        #pragma unroll
        for (int j = 0; j < 8; ++j) acc[j] = 0.f;

        if (is_x1) {
            const int* idx = x1 + (size_t)row * 8;
            u16x8 v[8];
            #pragma unroll
            for (int l = 0; l < 8; ++l) {
                const int tok = idx[l];
                v[l] = *reinterpret_cast<const u16x8*>(
                    ws + ((size_t)l * N_TOKENS + (size_t)tok) * SLICE_COLS + g * 8);
            }
            #pragma unroll
            for (int l = 0; l < 8; ++l)
                #pragma unroll
                for (int j = 0; j < 8; ++j) acc[j] += bf2f(v[l][j]);
        } else {
            const int r = row - n1;
            const int* idx = x2 + (size_t)r * 4;
            u16x8 v[4];
            #pragma unroll
            for (int l = 0; l < 4; ++l) {
                const int tok = idx[l];
                v[l] = *reinterpret_cast<const u16x8*>(
                    ws + ((size_t)l * N_TOKENS + (size_t)tok) * SLICE_COLS + g * 8);
            }
            #pragma unroll
            for (int l = 0; l < 4; ++l)
                #pragma unroll
                for (int j = 0; j < 8; ++j) acc[j] += bf2f(v[l][j]);
        }

        f32x4 lo = { acc[0], acc[1], acc[2], acc[3] };
        f32x4 hi = { acc[4], acc[5], acc[6], acc[7] };
        float* obase = out + (size_t)row * TOKEN_DIM + col;
        __builtin_nontemporal_store(lo, reinterpret_cast<f32x4*>(obase));
        __builtin_nontemporal_store(hi, reinterpret_cast<f32x4*>(obase) + 1);
    }
}

// ---- fallback: pure fp32 gather (if d_ws too small or odd shapes) ----
__global__ __launch_bounds__(256) void multi_embed_f32_kernel(
    const int* __restrict__ x1, const int* __restrict__ x2,
    const float* __restrict__ weight, float* __restrict__ out,
    int n1, int n2)
{
    const int row = blockIdx.x;
    const int c4  = threadIdx.x;
    f32x4 acc = (f32x4)(0.f);
    if (row < n1) {
        const int* idx = x1 + (size_t)row * 8;
        #pragma unroll
        for (int l = 0; l < 8; ++l) {
            const int tok = idx[l];
            acc += reinterpret_cast<const f32x4*>(
                weight + ((size_t)l * N_TOKENS + (size_t)tok) * TOKEN_DIM)[c4];
        }
    } else {
        const int r = row - n1;
        if (r >= n2) return;
        const int* idx = x2 + (size_t)r * 4;
        #pragma unroll
        for (int l = 0; l < 4; ++l) {
            const int tok = idx[l];
            acc += reinterpret_cast<const f32x4*>(
                weight + ((size_t)l * N_TOKENS + (size_t)tok) * TOKEN_DIM)[c4];
        }
    }
    f32x4* o = reinterpret_cast<f32x4*>(out + (size_t)row * TOKEN_DIM);
    __builtin_nontemporal_store(acc, &o[c4]);
}

extern "C" void kernel_launch(void* const* d_in, const int* in_sizes, int n_in,
                              void* d_out, int out_size, void* d_ws, size_t ws_size,
                              hipStream_t stream) {
    const int*   x1 = (const int*)d_in[0];
    const int*   x2 = (const int*)d_in[1];
    const float* w  = (const float*)d_in[2];
    float*       o  = (float*)d_out;

    int n1 = in_sizes[0] / 8;   // 8192
    int n2 = in_sizes[1] / 4;   // 8192
    const int rows = n1 + n2;

    const size_t wb_bytes = (size_t)SLICES * SLICE_ELEMS * sizeof(unsigned short);
    const bool shapes_ok = (n1 == 8192) && (n2 == 8192);

    if (ws_size >= wb_bytes && shapes_ok) {
        unsigned short* wb = (unsigned short*)d_ws;
        void* args[] = { (void*)&x1, (void*)&x2, (void*)&w, (void*)&wb,
                         (void*)&o, (void*)&n1, (void*)&n2 };
        hipError_t e = hipLaunchCooperativeKernel(
            (const void*)fused_embed_kernel, dim3(GRID_BLOCKS), dim3(256),
            args, 0, stream);
        if (e == hipSuccess) return;
        // cooperative unavailable -> two-kernel fallback (same math)
        convert_pack_kernel<<<256 * SLICES, 256, 0, stream>>>(w, wb);
        gather_packed_kernel<<<(rows / 64) * SLICES, 256, 0, stream>>>(
            x1, x2, wb, o, n1, n2);
    } else {
        multi_embed_f32_kernel<<<rows, 256, 0, stream>>>(x1, x2, w, o, n1, n2);
    }
}

// Round 7
// 39.080 us; speedup vs baseline: 3.7878x; 3.7878x over previous
//
#include <hip/hip_runtime.h>
#include <hip/hip_bf16.h>

// MultiEmbedding: out1[r,:] = sum_{l<8} W[l, x1[r,l], :]
//                 out2[r,:] = sum_{l<4} W[l, x2[r,l], :]
// W: [8, 1024, 1024] fp32, x1: [8192,8] i32, x2: [8192,4] i32.
//
// Two-kernel structure (R5; 34.9us). R6 lesson: do NOT fuse with grid.sync —
// the device-scope acquire invalidates per-XCD L2s and destroys wb residency
// (148us, 4x regression). Kernel boundaries preserve L2 lines.
//
// Pass 1 (convert_pack): W -> bf16 packed per column-slice
//   wb[slice][l*1024+tok][128], slice = blockIdx%8 -> XCD (round-robin).
//   NT loads for W (read-once; don't evict wb from L2), normal stores for wb
//   (keep each XCD's 2 MiB slice resident in its private 4 MiB L2).
// Pass 2 (gather): slice = blockIdx%8 (same XCD mapping) -> L2-hit reads.
//   Index loads software-pipelined (prefetch next iter's tokens). Output via
//   NT stores (never re-read; don't pollute L2).

#define TOKEN_DIM 1024
#define N_TOKENS  1024
#define N_LEVELS  8

#define SLICES      8
#define SLICE_COLS  128                        // TOKEN_DIM / SLICES
#define SLICE_ROWS  (N_LEVELS * N_TOKENS)      // 8192 (l,token) rows
#define SLICE_ELEMS ((size_t)SLICE_ROWS * SLICE_COLS)  // 1M bf16 = 2 MiB

#define ROWS_PER_BLOCK 64
#define ROWS_PER_ITER  16    // 256 threads / 16 col-groups

typedef float          f32x4 __attribute__((ext_vector_type(4)));
typedef int            i32x4 __attribute__((ext_vector_type(4)));
typedef unsigned short u16x4 __attribute__((ext_vector_type(4)));
typedef unsigned short u16x8 __attribute__((ext_vector_type(8)));

__device__ __forceinline__ unsigned short f2bf_rne(float f) {
    unsigned int u = __float_as_uint(f);
    u += 0x7fffu + ((u >> 16) & 1u);     // round-to-nearest-even
    return (unsigned short)(u >> 16);
}
__device__ __forceinline__ float bf2f(unsigned short u) {
    return __uint_as_float(((unsigned int)u) << 16);
}

// ---- pass 1: fp32 -> bf16, packed per slice, L2-warm ----
// blockIdx = chunk*8 + slice; 256 chunks x 32 rows = 8192 (l,tok) rows/slice.
__global__ __launch_bounds__(256) void convert_pack_kernel(
    const float* __restrict__ w, unsigned short* __restrict__ wb)
{
    const int slice  = blockIdx.x & 7;
    const int chunk  = blockIdx.x >> 3;      // 0..255
    const int lane_c = threadIdx.x & 31;     // 4 fp32 cols (16B)
    const int lrow   = threadIdx.x >> 5;     // 0..7
    const int row0   = chunk * 32;

    unsigned short* ws = wb + (size_t)slice * SLICE_ELEMS;

    #pragma unroll
    for (int it = 0; it < 4; ++it) {
        const int row = row0 + it * 8 + lrow;          // (l*1024 + tok)
        // NT load: W is read exactly once; do not allocate in L2 (would evict
        // the wb lines we are trying to keep resident for the gather pass).
        const f32x4 v = __builtin_nontemporal_load(
            reinterpret_cast<const f32x4*>(
                w + (size_t)row * TOKEN_DIM + slice * SLICE_COLS + lane_c * 4));
        u16x4 o;
        o.x = f2bf_rne(v.x); o.y = f2bf_rne(v.y);
        o.z = f2bf_rne(v.z); o.w = f2bf_rne(v.w);
        *reinterpret_cast<u16x4*>(
            ws + (size_t)row * SLICE_COLS + lane_c * 4) = o;   // normal store
    }
}

// ---- pass 2: packed, column-sliced gather with idx prefetch pipeline ----
// blockIdx = chunk*8 + slice. Thread: g = t&15 (8 cols), lr = t>>4 (16 rows).
__global__ __launch_bounds__(256) void gather_packed_kernel(
    const int* __restrict__ x1, const int* __restrict__ x2,
    const unsigned short* __restrict__ wb, float* __restrict__ out,
    int n1, int n2)
{
    const int slice = blockIdx.x & 7;
    const int chunk = blockIdx.x >> 3;
    const int row0  = chunk * ROWS_PER_BLOCK;
    const int g     = threadIdx.x & 15;
    const int lr    = threadIdx.x >> 4;

    const unsigned short* ws = wb + (size_t)slice * SLICE_ELEMS;
    const int col = slice * SLICE_COLS + g * 8;
    const int g8  = g * 8;

    const bool is_x1 = (row0 < n1);   // block-uniform (chunks never straddle)

    if (is_x1) {
        // prologue: indices for iteration 0
        const int* ip0 = x1 + (size_t)(row0 + lr) * 8;
        i32x4 tlo = *reinterpret_cast<const i32x4*>(ip0);
        i32x4 thi = *reinterpret_cast<const i32x4*>(ip0 + 4);

        #pragma unroll
        for (int it = 0; it < ROWS_PER_BLOCK / ROWS_PER_ITER; ++it) {
            const int row = row0 + it * ROWS_PER_ITER + lr;

            // prefetch next iteration's indices (hides idx latency under
            // this iteration's row loads + accumulate)
            i32x4 nlo, nhi;
            if (it < 3) {
                const int* np = x1 + (size_t)(row + ROWS_PER_ITER) * 8;
                nlo = *reinterpret_cast<const i32x4*>(np);
                nhi = *reinterpret_cast<const i32x4*>(np + 4);
            }

            const int tok[8] = { tlo.x, tlo.y, tlo.z, tlo.w,
                                 thi.x, thi.y, thi.z, thi.w };
            u16x8 v[8];
            #pragma unroll
            for (int l = 0; l < 8; ++l)
                v[l] = *reinterpret_cast<const u16x8*>(
                    ws + ((size_t)l * N_TOKENS + (size_t)tok[l]) * SLICE_COLS + g8);

            float acc[8];
            #pragma unroll
            for (int j = 0; j < 8; ++j) acc[j] = 0.f;
            #pragma unroll
            for (int l = 0; l < 8; ++l)
                #pragma unroll
                for (int j = 0; j < 8; ++j) acc[j] += bf2f(v[l][j]);

            f32x4 lo = { acc[0], acc[1], acc[2], acc[3] };
            f32x4 hi = { acc[4], acc[5], acc[6], acc[7] };
            float* obase = out + (size_t)row * TOKEN_DIM + col;
            __builtin_nontemporal_store(lo, reinterpret_cast<f32x4*>(obase));
            __builtin_nontemporal_store(hi, reinterpret_cast<f32x4*>(obase) + 1);

            tlo = nlo; thi = nhi;
        }
    } else {
        const int* ip0 = x2 + (size_t)(row0 - n1 + lr) * 4;
        i32x4 tc = *reinterpret_cast<const i32x4*>(ip0);

        #pragma unroll
        for (int it = 0; it < ROWS_PER_BLOCK / ROWS_PER_ITER; ++it) {
            const int row = row0 + it * ROWS_PER_ITER + lr;

            i32x4 nc;
            if (it < 3) {
                const int* np = x2 + (size_t)(row - n1 + ROWS_PER_ITER) * 4;
                nc = *reinterpret_cast<const i32x4*>(np);
            }

            const int tok[4] = { tc.x, tc.y, tc.z, tc.w };
            u16x8 v[4];
            #pragma unroll
            for (int l = 0; l < 4; ++l)
                v[l] = *reinterpret_cast<const u16x8*>(
                    ws + ((size_t)l * N_TOKENS + (size_t)tok[l]) * SLICE_COLS + g8);

            float acc[8];
            #pragma unroll
            for (int j = 0; j < 8; ++j) acc[j] = 0.f;
            #pragma unroll
            for (int l = 0; l < 4; ++l)
                #pragma unroll
                for (int j = 0; j < 8; ++j) acc[j] += bf2f(v[l][j]);

            f32x4 lo = { acc[0], acc[1], acc[2], acc[3] };
            f32x4 hi = { acc[4], acc[5], acc[6], acc[7] };
            float* obase = out + (size_t)row * TOKEN_DIM + col;
            __builtin_nontemporal_store(lo, reinterpret_cast<f32x4*>(obase));
            __builtin_nontemporal_store(hi, reinterpret_cast<f32x4*>(obase) + 1);

            tc = nc;
        }
    }
}

// ---- fallback: pure fp32 gather (if d_ws too small or odd shapes) ----
__global__ __launch_bounds__(256) void multi_embed_f32_kernel(
    const int* __restrict__ x1, const int* __restrict__ x2,
    const float* __restrict__ weight, float* __restrict__ out,
    int n1, int n2)
{
    const int row = blockIdx.x;
    const int c4  = threadIdx.x;
    f32x4 acc = (f32x4)(0.f);
    if (row < n1) {
        const int* idx = x1 + (size_t)row * 8;
        #pragma unroll
        for (int l = 0; l < 8; ++l) {
            const int tok = idx[l];
            acc += reinterpret_cast<const f32x4*>(
                weight + ((size_t)l * N_TOKENS + (size_t)tok) * TOKEN_DIM)[c4];
        }
    } else {
        const int r = row - n1;
        if (r >= n2) return;
        const int* idx = x2 + (size_t)r * 4;
        #pragma unroll
        for (int l = 0; l < 4; ++l) {
            const int tok = idx[l];
            acc += reinterpret_cast<const f32x4*>(
                weight + ((size_t)l * N_TOKENS + (size_t)tok) * TOKEN_DIM)[c4];
        }
    }
    f32x4* o = reinterpret_cast<f32x4*>(out + (size_t)row * TOKEN_DIM);
    __builtin_nontemporal_store(acc, &o[c4]);
}

extern "C" void kernel_launch(void* const* d_in, const int* in_sizes, int n_in,
                              void* d_out, int out_size, void* d_ws, size_t ws_size,
                              hipStream_t stream) {
    const int*   x1 = (const int*)d_in[0];
    const int*   x2 = (const int*)d_in[1];
    const float* w  = (const float*)d_in[2];
    float*       o  = (float*)d_out;

    const int n1 = in_sizes[0] / 8;   // 8192
    const int n2 = in_sizes[1] / 4;   // 8192
    const int rows = n1 + n2;

    const size_t wb_bytes = (size_t)SLICES * SLICE_ELEMS * sizeof(unsigned short);
    const bool shapes_ok = (n1 % ROWS_PER_BLOCK) == 0 && (rows % ROWS_PER_BLOCK) == 0;

    if (ws_size >= wb_bytes && shapes_ok) {
        unsigned short* wb = (unsigned short*)d_ws;
        convert_pack_kernel<<<256 * SLICES, 256, 0, stream>>>(w, wb);
        gather_packed_kernel<<<(rows / ROWS_PER_BLOCK) * SLICES, 256, 0, stream>>>(
            x1, x2, wb, o, n1, n2);
    } else {
        multi_embed_f32_kernel<<<rows, 256, 0, stream>>>(x1, x2, w, o, n1, n2);
    }
}

// Round 8
// 34.603 us; speedup vs baseline: 4.2779x; 1.1294x over previous
//
#include <hip/hip_runtime.h>
#include <hip/hip_bf16.h>

// MultiEmbedding: out1[r,:] = sum_{l<8} W[l, x1[r,l], :]
//                 out2[r,:] = sum_{l<4} W[l, x2[r,l], :]
// W: [8, 1024, 1024] fp32, x1: [8192,8] i32, x2: [8192,4] i32.
//
// Two-kernel structure (R5 baseline, 34.9us best).
// Journal: R6 grid.sync fusion = 148us (device-scope acquire invalidates
// per-XCD L2 -> wb residency destroyed). R7 NT W-loads + manual idx pipeline
// = 39.1us (broke compiler's full-unroll schedule; NT loads no help).
// R8: gather byte-identical to R5; convert restructured for 16B stores.
//
// Pass 1 (convert_pack): W -> bf16 packed per column-slice
//   wb[slice][l*1024+tok][128], slice = blockIdx%8 -> XCD (round-robin).
//   Normal loads/stores; each XCD's 2 MiB slice stays hot in its 4 MiB L2.
// Pass 2 (gather): slice = blockIdx%8 (same XCD mapping) -> L2-hit reads.
//   Output (never re-read) via NT stores.

#define TOKEN_DIM 1024
#define N_TOKENS  1024
#define N_LEVELS  8

#define SLICES      8
#define SLICE_COLS  128                        // TOKEN_DIM / SLICES
#define SLICE_ROWS  (N_LEVELS * N_TOKENS)      // 8192 (l,token) rows
#define SLICE_ELEMS ((size_t)SLICE_ROWS * SLICE_COLS)  // 1M bf16 = 2 MiB

#define ROWS_PER_BLOCK 64
#define ROWS_PER_ITER  16    // 256 threads / 16 col-groups

typedef float          f32x4 __attribute__((ext_vector_type(4)));
typedef unsigned short u16x4 __attribute__((ext_vector_type(4)));
typedef unsigned short u16x8 __attribute__((ext_vector_type(8)));

__device__ __forceinline__ unsigned short f2bf_rne(float f) {
    unsigned int u = __float_as_uint(f);
    u += 0x7fffu + ((u >> 16) & 1u);     // round-to-nearest-even
    return (unsigned short)(u >> 16);
}
__device__ __forceinline__ float bf2f(unsigned short u) {
    return __uint_as_float(((unsigned int)u) << 16);
}

// ---- pass 1: fp32 -> bf16, packed per slice, L2-warm, 16B stores ----
// blockIdx = chunk*8 + slice; 256 chunks x 32 rows = 8192 (l,tok) rows/slice.
// Thread: lane_c = t&15 (8 bf16 cols = 16B store), lrow = t>>4 (16 rows/iter).
__global__ __launch_bounds__(256) void convert_pack_kernel(
    const float* __restrict__ w, unsigned short* __restrict__ wb)
{
    const int slice  = blockIdx.x & 7;
    const int chunk  = blockIdx.x >> 3;      // 0..255
    const int lane_c = threadIdx.x & 15;     // 8 cols (16B out, 32B in)
    const int lrow   = threadIdx.x >> 4;     // 0..15
    const int row0   = chunk * 32;

    unsigned short* ws = wb + (size_t)slice * SLICE_ELEMS;

    #pragma unroll
    for (int it = 0; it < 2; ++it) {
        const int row = row0 + it * 16 + lrow;         // (l*1024 + tok)
        const float* src = w + (size_t)row * TOKEN_DIM + slice * SLICE_COLS + lane_c * 8;
        const f32x4 va = *reinterpret_cast<const f32x4*>(src);
        const f32x4 vb = *reinterpret_cast<const f32x4*>(src + 4);
        u16x8 o;
        o[0] = f2bf_rne(va.x); o[1] = f2bf_rne(va.y);
        o[2] = f2bf_rne(va.z); o[3] = f2bf_rne(va.w);
        o[4] = f2bf_rne(vb.x); o[5] = f2bf_rne(vb.y);
        o[6] = f2bf_rne(vb.z); o[7] = f2bf_rne(vb.w);
        *reinterpret_cast<u16x8*>(
            ws + (size_t)row * SLICE_COLS + lane_c * 8) = o;   // normal store
    }
}

// ---- pass 2: packed, column-sliced gather (byte-identical to R5) ----
// blockIdx = chunk*8 + slice. Thread: g = t&15 (8 cols), lr = t>>4 (16 rows).
__global__ __launch_bounds__(256) void gather_packed_kernel(
    const int* __restrict__ x1, const int* __restrict__ x2,
    const unsigned short* __restrict__ wb, float* __restrict__ out,
    int n1, int n2)
{
    const int slice = blockIdx.x & 7;
    const int chunk = blockIdx.x >> 3;
    const int row0  = chunk * ROWS_PER_BLOCK;
    const int g     = threadIdx.x & 15;
    const int lr    = threadIdx.x >> 4;

    const unsigned short* ws = wb + (size_t)slice * SLICE_ELEMS;
    const int col = slice * SLICE_COLS + g * 8;

    const bool is_x1 = (row0 < n1);   // chunks never straddle (n1 % 64 == 0)

    #pragma unroll
    for (int it = 0; it < ROWS_PER_BLOCK / ROWS_PER_ITER; ++it) {
        const int row = row0 + it * ROWS_PER_ITER + lr;

        float acc[8];
        #pragma unroll
        for (int j = 0; j < 8; ++j) acc[j] = 0.f;

        if (is_x1) {
            const int* idx = x1 + (size_t)row * 8;
            u16x8 v[8];
            #pragma unroll
            for (int l = 0; l < 8; ++l) {
                const int tok = idx[l];
                v[l] = *reinterpret_cast<const u16x8*>(
                    ws + ((size_t)l * N_TOKENS + (size_t)tok) * SLICE_COLS + g * 8);
            }
            #pragma unroll
            for (int l = 0; l < 8; ++l)
                #pragma unroll
                for (int j = 0; j < 8; ++j) acc[j] += bf2f(v[l][j]);
        } else {
            const int r = row - n1;
            const int* idx = x2 + (size_t)r * 4;
            u16x8 v[4];
            #pragma unroll
            for (int l = 0; l < 4; ++l) {
                const int tok = idx[l];
                v[l] = *reinterpret_cast<const u16x8*>(
                    ws + ((size_t)l * N_TOKENS + (size_t)tok) * SLICE_COLS + g * 8);
            }
            #pragma unroll
            for (int l = 0; l < 4; ++l)
                #pragma unroll
                for (int j = 0; j < 8; ++j) acc[j] += bf2f(v[l][j]);
        }

        f32x4 lo = { acc[0], acc[1], acc[2], acc[3] };
        f32x4 hi = { acc[4], acc[5], acc[6], acc[7] };
        float* obase = out + (size_t)row * TOKEN_DIM + col;
        __builtin_nontemporal_store(lo, reinterpret_cast<f32x4*>(obase));
        __builtin_nontemporal_store(hi, reinterpret_cast<f32x4*>(obase) + 1);
    }
}

// ---- fallback: pure fp32 gather (if d_ws too small or odd shapes) ----
__global__ __launch_bounds__(256) void multi_embed_f32_kernel(
    const int* __restrict__ x1, const int* __restrict__ x2,
    const float* __restrict__ weight, float* __restrict__ out,
    int n1, int n2)
{
    const int row = blockIdx.x;
    const int c4  = threadIdx.x;
    f32x4 acc = (f32x4)(0.f);
    if (row < n1) {
        const int* idx = x1 + (size_t)row * 8;
        #pragma unroll
        for (int l = 0; l < 8; ++l) {
            const int tok = idx[l];
            acc += reinterpret_cast<const f32x4*>(
                weight + ((size_t)l * N_TOKENS + (size_t)tok) * TOKEN_DIM)[c4];
        }
    } else {
        const int r = row - n1;
        if (r >= n2) return;
        const int* idx = x2 + (size_t)r * 4;
        #pragma unroll
        for (int l = 0; l < 4; ++l) {
            const int tok = idx[l];
            acc += reinterpret_cast<const f32x4*>(
                weight + ((size_t)l * N_TOKENS + (size_t)tok) * TOKEN_DIM)[c4];
        }
    }
    f32x4* o = reinterpret_cast<f32x4*>(out + (size_t)row * TOKEN_DIM);
    __builtin_nontemporal_store(acc, &o[c4]);
}

extern "C" void kernel_launch(void* const* d_in, const int* in_sizes, int n_in,
                              void* d_out, int out_size, void* d_ws, size_t ws_size,
                              hipStream_t stream) {
    const int*   x1 = (const int*)d_in[0];
    const int*   x2 = (const int*)d_in[1];
    const float* w  = (const float*)d_in[2];
    float*       o  = (float*)d_out;

    const int n1 = in_sizes[0] / 8;   // 8192
    const int n2 = in_sizes[1] / 4;   // 8192
    const int rows = n1 + n2;

    const size_t wb_bytes = (size_t)SLICES * SLICE_ELEMS * sizeof(unsigned short);
    const bool shapes_ok = (n1 % ROWS_PER_BLOCK) == 0 && (rows % ROWS_PER_BLOCK) == 0;

    if (ws_size >= wb_bytes && shapes_ok) {
        unsigned short* wb = (unsigned short*)d_ws;
        convert_pack_kernel<<<256 * SLICES, 256, 0, stream>>>(w, wb);
        gather_packed_kernel<<<(rows / ROWS_PER_BLOCK) * SLICES, 256, 0, stream>>>(
            x1, x2, wb, o, n1, n2);
    } else {
        multi_embed_f32_kernel<<<rows, 256, 0, stream>>>(x1, x2, w, o, n1, n2);
    }
}

// Round 9
// 30.613 us; speedup vs baseline: 4.8354x; 1.1303x over previous
//
#include <hip/hip_runtime.h>
#include <hip/hip_bf16.h>

// MultiEmbedding: out1[r,:] = sum_{l<8} W[l, x1[r,l], :]
//                 out2[r,:] = sum_{l<4} W[l, x2[r,l], :]
// W: [8, 1024, 1024] fp32, x1: [8192,8] i32, x2: [8192,4] i32.
//
// Journal: R2 naive fp32 61us (FETCH 169MB). R3 bf16 table 47.7. R5 slice-
// packed bf16 + XCD-pinned slices 34.9. R6 grid.sync fusion 148us (agent
// acquire invalidates per-XCD L2 -> never fence between warm-up and consume).
// R7 NT W-loads + manual idx pipeline 39.1 (broke compiler schedule). R8 16B
// convert stores 34.6 (neutral). R9: balanced gather blocks (32 x1 + 32 x2
// rows each -> uniform 384 row-gathers/block, flat tail); inner loops
// unchanged from R8.
//
// Pass 1 (convert_pack): W -> bf16 packed per column-slice
//   wb[slice][l*1024+tok][128], slice = blockIdx%8 -> XCD (round-robin).
//   Each XCD's 2 MiB slice stays hot in its private 4 MiB L2.
// Pass 2 (gather): slice = blockIdx%8 (same XCD mapping) -> L2-hit reads.
//   Output (never re-read) via NT stores.

#define TOKEN_DIM 1024
#define N_TOKENS  1024
#define N_LEVELS  8

#define SLICES      8
#define SLICE_COLS  128                        // TOKEN_DIM / SLICES
#define SLICE_ROWS  (N_LEVELS * N_TOKENS)      // 8192 (l,token) rows
#define SLICE_ELEMS ((size_t)SLICE_ROWS * SLICE_COLS)  // 1M bf16 = 2 MiB

#define ROWS_PER_HALF 32     // x1 rows and x2 rows per gather block
#define ROWS_PER_ITER 16     // 256 threads / 16 col-groups

typedef float          f32x4 __attribute__((ext_vector_type(4)));
typedef unsigned short u16x4 __attribute__((ext_vector_type(4)));
typedef unsigned short u16x8 __attribute__((ext_vector_type(8)));

__device__ __forceinline__ unsigned short f2bf_rne(float f) {
    unsigned int u = __float_as_uint(f);
    u += 0x7fffu + ((u >> 16) & 1u);     // round-to-nearest-even
    return (unsigned short)(u >> 16);
}
__device__ __forceinline__ float bf2f(unsigned short u) {
    return __uint_as_float(((unsigned int)u) << 16);
}

// ---- pass 1: fp32 -> bf16, packed per slice, L2-warm, 16B stores (R8) ----
__global__ __launch_bounds__(256) void convert_pack_kernel(
    const float* __restrict__ w, unsigned short* __restrict__ wb)
{
    const int slice  = blockIdx.x & 7;
    const int chunk  = blockIdx.x >> 3;      // 0..255
    const int lane_c = threadIdx.x & 15;     // 8 cols (16B out, 32B in)
    const int lrow   = threadIdx.x >> 4;     // 0..15
    const int row0   = chunk * 32;

    unsigned short* ws = wb + (size_t)slice * SLICE_ELEMS;

    #pragma unroll
    for (int it = 0; it < 2; ++it) {
        const int row = row0 + it * 16 + lrow;         // (l*1024 + tok)
        const float* src = w + (size_t)row * TOKEN_DIM + slice * SLICE_COLS + lane_c * 8;
        const f32x4 va = *reinterpret_cast<const f32x4*>(src);
        const f32x4 vb = *reinterpret_cast<const f32x4*>(src + 4);
        u16x8 o;
        o[0] = f2bf_rne(va.x); o[1] = f2bf_rne(va.y);
        o[2] = f2bf_rne(va.z); o[3] = f2bf_rne(va.w);
        o[4] = f2bf_rne(vb.x); o[5] = f2bf_rne(vb.y);
        o[6] = f2bf_rne(vb.z); o[7] = f2bf_rne(vb.w);
        *reinterpret_cast<u16x8*>(
            ws + (size_t)row * SLICE_COLS + lane_c * 8) = o;   // normal store
    }
}

// ---- pass 2: packed, column-sliced, WORK-BALANCED gather ----
// blockIdx = chunk*8 + slice; chunk 0..255. Each block: 32 x1 rows then
// 32 x2 rows (384 row-gathers, uniform). Thread: g = t&15 (8 cols),
// lr = t>>4 (16 rows per iteration). Inner loops identical to R8.
__global__ __launch_bounds__(256) void gather_packed_kernel(
    const int* __restrict__ x1, const int* __restrict__ x2,
    const unsigned short* __restrict__ wb, float* __restrict__ out,
    int n1, int n2)
{
    const int slice = blockIdx.x & 7;
    const int chunk = blockIdx.x >> 3;
    const int g     = threadIdx.x & 15;
    const int lr    = threadIdx.x >> 4;

    const unsigned short* ws = wb + (size_t)slice * SLICE_ELEMS;
    const int col = slice * SLICE_COLS + g * 8;
    const int row0 = chunk * ROWS_PER_HALF;

    // ---- x1 half: rows [row0, row0+32), 8 levels each ----
    #pragma unroll
    for (int it = 0; it < ROWS_PER_HALF / ROWS_PER_ITER; ++it) {
        const int row = row0 + it * ROWS_PER_ITER + lr;

        float acc[8];
        #pragma unroll
        for (int j = 0; j < 8; ++j) acc[j] = 0.f;

        const int* idx = x1 + (size_t)row * 8;
        u16x8 v[8];
        #pragma unroll
        for (int l = 0; l < 8; ++l) {
            const int tok = idx[l];
            v[l] = *reinterpret_cast<const u16x8*>(
                ws + ((size_t)l * N_TOKENS + (size_t)tok) * SLICE_COLS + g * 8);
        }
        #pragma unroll
        for (int l = 0; l < 8; ++l)
            #pragma unroll
            for (int j = 0; j < 8; ++j) acc[j] += bf2f(v[l][j]);

        f32x4 lo = { acc[0], acc[1], acc[2], acc[3] };
        f32x4 hi = { acc[4], acc[5], acc[6], acc[7] };
        float* obase = out + (size_t)row * TOKEN_DIM + col;
        __builtin_nontemporal_store(lo, reinterpret_cast<f32x4*>(obase));
        __builtin_nontemporal_store(hi, reinterpret_cast<f32x4*>(obase) + 1);
    }

    // ---- x2 half: rows [row0, row0+32), 4 levels each ----
    #pragma unroll
    for (int it = 0; it < ROWS_PER_HALF / ROWS_PER_ITER; ++it) {
        const int row = row0 + it * ROWS_PER_ITER + lr;

        float acc[8];
        #pragma unroll
        for (int j = 0; j < 8; ++j) acc[j] = 0.f;

        const int* idx = x2 + (size_t)row * 4;
        u16x8 v[4];
        #pragma unroll
        for (int l = 0; l < 4; ++l) {
            const int tok = idx[l];
            v[l] = *reinterpret_cast<const u16x8*>(
                ws + ((size_t)l * N_TOKENS + (size_t)tok) * SLICE_COLS + g * 8);
        }
        #pragma unroll
        for (int l = 0; l < 4; ++l)
            #pragma unroll
            for (int j = 0; j < 8; ++j) acc[j] += bf2f(v[l][j]);

        f32x4 lo = { acc[0], acc[1], acc[2], acc[3] };
        f32x4 hi = { acc[4], acc[5], acc[6], acc[7] };
        float* obase = out + (size_t)(n1 + row) * TOKEN_DIM + col;
        __builtin_nontemporal_store(lo, reinterpret_cast<f32x4*>(obase));
        __builtin_nontemporal_store(hi, reinterpret_cast<f32x4*>(obase) + 1);
    }
}

// ---- fallback: pure fp32 gather (if d_ws too small or odd shapes) ----
__global__ __launch_bounds__(256) void multi_embed_f32_kernel(
    const int* __restrict__ x1, const int* __restrict__ x2,
    const float* __restrict__ weight, float* __restrict__ out,
    int n1, int n2)
{
    const int row = blockIdx.x;
    const int c4  = threadIdx.x;
    f32x4 acc = (f32x4)(0.f);
    if (row < n1) {
        const int* idx = x1 + (size_t)row * 8;
        #pragma unroll
        for (int l = 0; l < 8; ++l) {
            const int tok = idx[l];
            acc += reinterpret_cast<const f32x4*>(
                weight + ((size_t)l * N_TOKENS + (size_t)tok) * TOKEN_DIM)[c4];
        }
    } else {
        const int r = row - n1;
        if (r >= n2) return;
        const int* idx = x2 + (size_t)r * 4;
        #pragma unroll
        for (int l = 0; l < 4; ++l) {
            const int tok = idx[l];
            acc += reinterpret_cast<const f32x4*>(
                weight + ((size_t)l * N_TOKENS + (size_t)tok) * TOKEN_DIM)[c4];
        }
    }
    f32x4* o = reinterpret_cast<f32x4*>(out + (size_t)row * TOKEN_DIM);
    __builtin_nontemporal_store(acc, &o[c4]);
}

extern "C" void kernel_launch(void* const* d_in, const int* in_sizes, int n_in,
                              void* d_out, int out_size, void* d_ws, size_t ws_size,
                              hipStream_t stream) {
    const int*   x1 = (const int*)d_in[0];
    const int*   x2 = (const int*)d_in[1];
    const float* w  = (const float*)d_in[2];
    float*       o  = (float*)d_out;

    const int n1 = in_sizes[0] / 8;   // 8192
    const int n2 = in_sizes[1] / 4;   // 8192

    const size_t wb_bytes = (size_t)SLICES * SLICE_ELEMS * sizeof(unsigned short);
    const bool shapes_ok = (n1 == n2) && (n1 % ROWS_PER_HALF) == 0;

    if (ws_size >= wb_bytes && shapes_ok) {
        unsigned short* wb = (unsigned short*)d_ws;
        convert_pack_kernel<<<256 * SLICES, 256, 0, stream>>>(w, wb);
        gather_packed_kernel<<<(n1 / ROWS_PER_HALF) * SLICES, 256, 0, stream>>>(
            x1, x2, wb, o, n1, n2);
    } else {
        multi_embed_f32_kernel<<<n1 + n2, 256, 0, stream>>>(x1, x2, w, o, n1, n2);
    }
}